// Round 6
// baseline (8152.883 us; speedup 1.0000x reference)
//
#include <hip/hip_runtime.h>
#include <hip/hip_bf16.h>
#include <stdint.h>
#include <stddef.h>

namespace {

typedef _Float16 f16;
typedef __attribute__((ext_vector_type(8))) _Float16 f16x8;
typedef __attribute__((ext_vector_type(4))) _Float16 f16x4;
typedef __attribute__((ext_vector_type(4))) float f32x4;

constexpr int CB = 32;                  // batch
constexpr int CS = 4;                   // states
constexpr int CV = 20000;               // vocab
constexpr int CVP = 20224;              // padded vocab (79 tiles * 256)
constexpr int NTILE = 79;               // vocab tiles of 256
constexpr int CH = 512;                 // hidden
constexpr int CBEAM = 5;
constexpr int CT = 20;                  // MAX_STEPS
constexpr int CNR = CB * CS * CBEAM;    // 640 rows
constexpr int CSB = CS * CBEAM;         // 20
constexpr int CNP = CB * CS * CV;       // packed mask bytes
constexpr float VNF = -1e20f;
constexpr float NEGINF = -3.402823466e+38f;
constexpr int IMAX = 0x7fffffff;

// f32 -> scaled f16 split: x*256 = h + l (RNE), exact power-of-2 scale
__device__ __forceinline__ void f2h2(float x, f16& h, f16& l) {
  float xs = x * 256.0f;
  h = (f16)xs;
  l = (f16)(xs - (float)h);
}

// ---------------- state_transform dtype detection ----------------
// modes: 0=u8/bool bytes, 1=int32, 2=int64(low word), 3=float32
__global__ void detect_mode_k(const unsigned int* __restrict__ w, int* __restrict__ mode) {
  if (threadIdx.x != 0 || blockIdx.x != 0) return;
  int all01 = 1, odd1 = 0, f1 = 0;
  for (int i = 0; i < 256; ++i) {
    unsigned int x = w[i];
    if (x > 1u) all01 = 0;
    if ((i & 1) && x == 1u) odd1++;
    if (x == 0x3f800000u) f1++;
  }
  int md;
  if (f1 > 128) md = 3;
  else if (all01) md = (odd1 > 8) ? 1 : 2;
  else md = 0;
  *mode = md;
}

// pack mask nibbles: pm[(b*CS+ss)*CV + v] bit st = state_transform[b,ss,st,v] != 0
__global__ void convert_pack_k(const void* __restrict__ st, unsigned char* __restrict__ pm,
                               const int* __restrict__ mode) {
  int md = *mode;
  for (int i = blockIdx.x * blockDim.x + threadIdx.x; i < CNP; i += gridDim.x * blockDim.x) {
    int v = i % CV;
    int bs = i / CV;
    size_t base = (size_t)bs * 4 * CV + v;
    unsigned char r = 0;
#pragma unroll
    for (int s = 0; s < 4; ++s) {
      size_t idx = base + (size_t)s * CV;
      unsigned char bit;
      if (md == 0)      bit = ((const unsigned char*)st)[idx] != 0;
      else if (md == 1) bit = ((const unsigned int*)st)[idx] != 0;
      else if (md == 2) bit = ((const unsigned int*)st)[2 * idx] != 0;
      else              bit = (((const unsigned int*)st)[idx] & 0x7fffffffu) != 0;
      r |= (unsigned char)(bit << s);
    }
    pm[i] = r;
  }
}

// ---------------- W_out [512][20000] f32 -> BT hi/lo [20224][512] f16 scaled ----------
__global__ __launch_bounds__(256) void conv_wout_k(const float* __restrict__ W,
                                                   f16* __restrict__ BTh,
                                                   f16* __restrict__ BTl) {
  __shared__ float t[64][65];
  int n0 = blockIdx.x * 64, k0 = blockIdx.y * 64;
  int tid = threadIdx.x;
  int c = tid & 63, r4 = tid >> 6;
#pragma unroll
  for (int i = 0; i < 16; ++i) {
    int kr = r4 + i * 4;
    int n = n0 + c;
    t[kr][c] = (n < CV) ? W[(size_t)(k0 + kr) * CV + n] : 0.f;
  }
  __syncthreads();
#pragma unroll
  for (int i = 0; i < 16; ++i) {
    int nr = r4 + i * 4;
    float x = t[c][nr];  // = W[k0+c][n0+nr]
    f16 h, l;
    f2h2(x, h, l);
    size_t o = (size_t)(n0 + nr) * CH + k0 + c;
    BTh[o] = h;
    BTl[o] = l;
  }
}

// ---------------- img @ W_im (step-invariant) ----------------
__global__ __launch_bounds__(256) void img_proj_k(const float* __restrict__ img,
                                                  const float* __restrict__ Wim,
                                                  float* __restrict__ out) {
  int b = blockIdx.x, tid = threadIdx.x;
  __shared__ float simg[2048];
  for (int i = tid; i < 2048; i += 256) simg[i] = img[b * 2048 + i];
  __syncthreads();
  int c0 = tid * 2;
  float a0 = 0.f, a1 = 0.f;
  for (int k = 0; k < 2048; ++k) {
    float x = simg[k];
    float2 w = *(const float2*)&Wim[(size_t)k * CH + c0];
    a0 = fmaf(x, w.x, a0);
    a1 = fmaf(x, w.y, a1);
  }
  out[b * CH + c0] = a0;
  out[b * CH + c0 + 1] = a1;
}

// ---------------- h0 = tanh(emb[start] + img_proj) (+ scaled f16 split) --------------
__global__ void init_h_k(const float* __restrict__ emb, const int* __restrict__ start,
                         const float* __restrict__ imgp, float* __restrict__ H0,
                         f16* __restrict__ Hh, f16* __restrict__ Hl) {
  int b = blockIdx.x, tid = threadIdx.x;
  int tok = start[b];
  for (int c = tid; c < CH; c += 256) {
    float v = tanhf(emb[(size_t)tok * CH + c] + imgp[b * CH + c]);
    H0[b * CH + c] = v;
    f16 h, l;
    f2h2(v, h, l);
    Hh[b * CH + c] = h;
    Hl[b * CH + c] = l;
  }
}

// ---------------- small f32 GEMM with row gather + tanh epilogue + f16 emit ----------
template <int BM, int BN, int KB, int MT, int NT>
__global__ __launch_bounds__(256) void gemm_k(
    const float* __restrict__ A, const int* __restrict__ rowmap,
    const float* __restrict__ Bm, float* __restrict__ C,
    int M, int N, int K,
    const int* __restrict__ tok, const float* __restrict__ emb,
    const float* __restrict__ imgp, f16* __restrict__ Hh, f16* __restrict__ Hl) {
  constexpr int TX = BN / NT;
  constexpr int TY = BM / MT;
  static_assert(TX * TY == 256, "thread count");
  __shared__ float As[KB][BM + 4];
  __shared__ float Bs[KB][BN + 4];
  const int bm = blockIdx.y * BM;
  const int bn = blockIdx.x * BN;
  const int tid = threadIdx.x;
  const int tx = tid % TX, ty = tid / TX;
  float acc[MT][NT];
#pragma unroll
  for (int i = 0; i < MT; ++i)
#pragma unroll
    for (int j = 0; j < NT; ++j) acc[i][j] = 0.f;

  for (int k0 = 0; k0 < K; k0 += KB) {
    constexpr int AIT = BM * KB / 4 / 256;
#pragma unroll
    for (int it = 0; it < AIT; ++it) {
      int i = tid + it * 256;
      int r = i / (KB / 4);
      int kq = i % (KB / 4);
      int row = bm + r;
      float4 v = make_float4(0.f, 0.f, 0.f, 0.f);
      if (row < M) {
        int sr = rowmap ? rowmap[row] : row;
        v = *(const float4*)&A[(size_t)sr * K + k0 + kq * 4];
      }
      As[kq * 4 + 0][r] = v.x;
      As[kq * 4 + 1][r] = v.y;
      As[kq * 4 + 2][r] = v.z;
      As[kq * 4 + 3][r] = v.w;
    }
    constexpr int BIT = KB * BN / 4 / 256;
#pragma unroll
    for (int it = 0; it < BIT; ++it) {
      int i = tid + it * 256;
      int kk = i / (BN / 4);
      int cq = i % (BN / 4);
      int col = bn + cq * 4;
      float4 v = make_float4(0.f, 0.f, 0.f, 0.f);
      if (col < N) v = *(const float4*)&Bm[(size_t)(k0 + kk) * N + col];
      *(float4*)&Bs[kk][cq * 4] = v;
    }
    __syncthreads();
#pragma unroll 8
    for (int kk = 0; kk < KB; ++kk) {
      float a[MT], bb[NT];
#pragma unroll
      for (int i = 0; i < MT; ++i) a[i] = As[kk][ty * MT + i];
#pragma unroll
      for (int j = 0; j < NT; ++j) bb[j] = Bs[kk][tx * NT + j];
#pragma unroll
      for (int i = 0; i < MT; ++i)
#pragma unroll
        for (int j = 0; j < NT; ++j) acc[i][j] = fmaf(a[i], bb[j], acc[i][j]);
    }
    __syncthreads();
  }
#pragma unroll
  for (int i = 0; i < MT; ++i) {
    int row = bm + ty * MT + i;
    if (row < M) {
#pragma unroll
      for (int j4 = 0; j4 < NT / 4; ++j4) {
        int col = bn + tx * NT + j4 * 4;
        if (col < N) {
          float4 v;
          v.x = acc[i][j4 * 4 + 0];
          v.y = acc[i][j4 * 4 + 1];
          v.z = acc[i][j4 * 4 + 2];
          v.w = acc[i][j4 * 4 + 3];
          size_t eb = (size_t)tok[row] * N;
          int ib = (row / CSB) * N;
          v.x = tanhf(v.x + emb[eb + col + 0] + imgp[ib + col + 0]);
          v.y = tanhf(v.y + emb[eb + col + 1] + imgp[ib + col + 1]);
          v.z = tanhf(v.z + emb[eb + col + 2] + imgp[ib + col + 2]);
          v.w = tanhf(v.w + emb[eb + col + 3] + imgp[ib + col + 3]);
          *(float4*)&C[(size_t)row * N + col] = v;
          f16 h0, h1, h2, h3, l0, l1, l2, l3;
          f2h2(v.x, h0, l0);
          f2h2(v.y, h1, l1);
          f2h2(v.z, h2, l2);
          f2h2(v.w, h3, l3);
          f16x4 hv = {h0, h1, h2, h3};
          f16x4 lv = {l0, l1, l2, l3};
          *(f16x4*)&Hh[(size_t)row * N + col] = hv;
          *(f16x4*)&Hl[(size_t)row * N + col] = lv;
        }
      }
    }
  }
}

// ---------------- sorted 5-list in named registers ----------------
struct L5 {
  float v0, v1, v2, v3, v4;
  int i0, i1, i2, i3, i4;
};

__device__ __forceinline__ void initL(L5& l) {
  l.v0 = l.v1 = l.v2 = l.v3 = l.v4 = NEGINF;
  l.i0 = l.i1 = l.i2 = l.i3 = l.i4 = IMAX;
}

__device__ __forceinline__ void insL(L5& l, float val, int idx) {
  if (!(val > l.v4)) return;  // strict >: equal values keep earlier (smaller) index first
  if (val > l.v0) {
    l.v4 = l.v3; l.i4 = l.i3; l.v3 = l.v2; l.i3 = l.i2; l.v2 = l.v1; l.i2 = l.i1;
    l.v1 = l.v0; l.i1 = l.i0; l.v0 = val; l.i0 = idx;
  } else if (val > l.v1) {
    l.v4 = l.v3; l.i4 = l.i3; l.v3 = l.v2; l.i3 = l.i2; l.v2 = l.v1; l.i2 = l.i1;
    l.v1 = val; l.i1 = idx;
  } else if (val > l.v2) {
    l.v4 = l.v3; l.i4 = l.i3; l.v3 = l.v2; l.i3 = l.i2; l.v2 = val; l.i2 = idx;
  } else if (val > l.v3) {
    l.v4 = l.v3; l.i4 = l.i3; l.v3 = val; l.i3 = idx;
  } else {
    l.v4 = val; l.i4 = idx;
  }
}

// merge sorted A,B -> top5 into A (val desc, idx asc)
__device__ __forceinline__ void mergeL(L5& A, L5 B) {
  float o0, o1, o2, o3, o4;
  int q0, q1, q2, q3, q4;
#define MSTEP(OV, OI)                                                                    \
  {                                                                                      \
    bool ta = (A.v0 > B.v0) || (A.v0 == B.v0 && A.i0 < B.i0);                            \
    if (ta) {                                                                            \
      OV = A.v0; OI = A.i0;                                                              \
      A.v0 = A.v1; A.i0 = A.i1; A.v1 = A.v2; A.i1 = A.i2; A.v2 = A.v3; A.i2 = A.i3;      \
      A.v3 = A.v4; A.i3 = A.i4; A.v4 = NEGINF; A.i4 = IMAX;                              \
    } else {                                                                             \
      OV = B.v0; OI = B.i0;                                                              \
      B.v0 = B.v1; B.i0 = B.i1; B.v1 = B.v2; B.i1 = B.i2; B.v2 = B.v3; B.i2 = B.i3;      \
      B.v3 = B.v4; B.i3 = B.i4; B.v4 = NEGINF; B.i4 = IMAX;                              \
    }                                                                                    \
  }
  MSTEP(o0, q0) MSTEP(o1, q1) MSTEP(o2, q2) MSTEP(o3, q3) MSTEP(o4, q4)
#undef MSTEP
  A.v0 = o0; A.v1 = o1; A.v2 = o2; A.v3 = o3; A.v4 = o4;
  A.i0 = q0; A.i1 = q1; A.i2 = q2; A.i3 = q3; A.i4 = q4;
}

__device__ __forceinline__ L5 shflxL(const L5& a, int off) {
  L5 r;
  r.v0 = __shfl_xor(a.v0, off); r.v1 = __shfl_xor(a.v1, off); r.v2 = __shfl_xor(a.v2, off);
  r.v3 = __shfl_xor(a.v3, off); r.v4 = __shfl_xor(a.v4, off);
  r.i0 = __shfl_xor(a.i0, off); r.i1 = __shfl_xor(a.i1, off); r.i2 = __shfl_xor(a.i2, off);
  r.i3 = __shfl_xor(a.i3, off); r.i4 = __shfl_xor(a.i4, off);
  return r;
}

// ---------------- fused MFMA GEMM + masked top-5 + lse partials ----------------------
// Output-transposed MFMA: D row = vocab (lq*4+rr + vf*16), D col = batch (l16)
// Block: 4 waves; wave w covers vocab [tile*256 + w*64, +64); batch rows bty..bty+63.
// Writes per (vocab tile, row): per-st top5 (raw logits, global col idx) + (max, sum).
template <bool INIT>
__global__ __launch_bounds__(256) void fused_gemm_k(
    const f16* __restrict__ Ah, const f16* __restrict__ Al,
    const f16* __restrict__ BTh, const f16* __restrict__ BTl,
    const unsigned char* __restrict__ pmask,
    float* __restrict__ pv, unsigned short* __restrict__ pi, float* __restrict__ pms) {
  const int tile = blockIdx.x;
  const int bty = blockIdx.y * 64;
  const int tid = threadIdx.x;
  const int w = tid >> 6;
  const int lane = tid & 63;
  const int l16 = lane & 15, lq = lane >> 4;
  const int vwave = tile * 256 + w * 64;

  const f16* pvh = BTh + (size_t)(vwave + l16) * CH + lq * 8;
  const f16* pvl = BTl + (size_t)(vwave + l16) * CH + lq * 8;
  const f16* pbh = Ah + (size_t)(bty + l16) * CH + lq * 8;
  const f16* pbl = Al + (size_t)(bty + l16) * CH + lq * 8;

  f32x4 acc[4][4] = {};  // [vf][bt]
  for (int k0 = 0; k0 < CH; k0 += 32) {
    f16x8 vh[4], vl[4], bh[4], bl[4];
#pragma unroll
    for (int i = 0; i < 4; ++i) {
      vh[i] = *(const f16x8*)(pvh + (size_t)i * 16 * CH + k0);
      vl[i] = *(const f16x8*)(pvl + (size_t)i * 16 * CH + k0);
      bh[i] = *(const f16x8*)(pbh + (size_t)i * 16 * CH + k0);
      bl[i] = *(const f16x8*)(pbl + (size_t)i * 16 * CH + k0);
    }
#pragma unroll
    for (int vf = 0; vf < 4; ++vf)
#pragma unroll
      for (int bt = 0; bt < 4; ++bt) {
        acc[vf][bt] = __builtin_amdgcn_mfma_f32_16x16x32_f16(vh[vf], bh[bt], acc[vf][bt], 0, 0, 0);
        acc[vf][bt] = __builtin_amdgcn_mfma_f32_16x16x32_f16(vh[vf], bl[bt], acc[vf][bt], 0, 0, 0);
        acc[vf][bt] = __builtin_amdgcn_mfma_f32_16x16x32_f16(vl[vf], bh[bt], acc[vf][bt], 0, 0, 0);
      }
  }

  __shared__ float lv[4][64][4][5];
  __shared__ unsigned short li[4][64][4][5];
  __shared__ float lms[4][64][2];

#pragma unroll
  for (int bt = 0; bt < 4; ++bt) {
    const int btrow = bty + bt * 16 + l16;  // this lane's logits row
    int mrow;
    if (INIT) mrow = min(btrow, CB - 1) * CS;
    else {
      int b = btrow / CSB;
      int ss = (btrow % CSB) / CBEAM;
      mrow = b * CS + ss;
    }
    const unsigned char* pmrow = pmask + (size_t)mrow * CV;
    float xv[4][4];
    unsigned int msk[4];
    float mloc = NEGINF;
#pragma unroll
    for (int vf = 0; vf < 4; ++vf) {
      int cb = vwave + vf * 16 + lq * 4;
      msk[vf] = *(const unsigned int*)(pmrow + cb);  // pmask padded; invalid gated below
#pragma unroll
      for (int rr = 0; rr < 4; ++rr) {
        float x = acc[vf][bt][rr] * (1.0f / 65536.0f);
        bool ok = (cb + rr) < CV;
        xv[vf][rr] = ok ? x : NEGINF;
        if (ok) mloc = fmaxf(mloc, x);
      }
    }
    float sloc = 0.f;
    L5 ls0, ls1, ls2, ls3;
    initL(ls0); initL(ls1); initL(ls2); initL(ls3);
#pragma unroll
    for (int vf = 0; vf < 4; ++vf) {
      int cb = vwave + vf * 16 + lq * 4;
#pragma unroll
      for (int rr = 0; rr < 4; ++rr) {
        int col = cb + rr;
        if (col < CV) {
          float x = xv[vf][rr];
          sloc += expf(x - mloc);
          unsigned int bits = msk[vf] >> (rr * 8);
          if (bits & 1u) insL(ls0, x, col);
          if (bits & 2u) insL(ls1, x, col);
          if (bits & 4u) insL(ls2, x, col);
          if (bits & 8u) insL(ls3, x, col);
        }
      }
    }
    // merge across lq (lanes differing in bits 4,5)
#pragma unroll
    for (int off = 16; off <= 32; off <<= 1) {
      mergeL(ls0, shflxL(ls0, off));
      mergeL(ls1, shflxL(ls1, off));
      mergeL(ls2, shflxL(ls2, off));
      mergeL(ls3, shflxL(ls3, off));
      float m2 = __shfl_xor(mloc, off);
      float s2 = __shfl_xor(sloc, off);
      float mn = fmaxf(mloc, m2);
      sloc = sloc * expf(mloc - mn) + s2 * expf(m2 - mn);
      mloc = mn;
    }
    if (lq == 0) {
      int lrow = bt * 16 + l16;
#define PUT(L, ST)                                                                      \
      lv[w][lrow][ST][0] = L.v0; lv[w][lrow][ST][1] = L.v1; lv[w][lrow][ST][2] = L.v2;  \
      lv[w][lrow][ST][3] = L.v3; lv[w][lrow][ST][4] = L.v4;                             \
      li[w][lrow][ST][0] = (unsigned short)L.i0; li[w][lrow][ST][1] = (unsigned short)L.i1; \
      li[w][lrow][ST][2] = (unsigned short)L.i2; li[w][lrow][ST][3] = (unsigned short)L.i3; \
      li[w][lrow][ST][4] = (unsigned short)L.i4;
      PUT(ls0, 0) PUT(ls1, 1) PUT(ls2, 2) PUT(ls3, 3)
#undef PUT
      lms[w][lrow][0] = mloc;
      lms[w][lrow][1] = sloc;
    }
  }
  __syncthreads();

  // block-end: merge 4 waves per (row, st); 256 threads = 64 rows x 4 st
  {
    int row64 = tid >> 2, st = tid & 3;
    L5 A;
    A.v0 = lv[0][row64][st][0]; A.v1 = lv[0][row64][st][1]; A.v2 = lv[0][row64][st][2];
    A.v3 = lv[0][row64][st][3]; A.v4 = lv[0][row64][st][4];
    A.i0 = li[0][row64][st][0]; A.i1 = li[0][row64][st][1]; A.i2 = li[0][row64][st][2];
    A.i3 = li[0][row64][st][3]; A.i4 = li[0][row64][st][4];
#pragma unroll
    for (int ww = 1; ww < 4; ++ww) {
      L5 B;
      B.v0 = lv[ww][row64][st][0]; B.v1 = lv[ww][row64][st][1]; B.v2 = lv[ww][row64][st][2];
      B.v3 = lv[ww][row64][st][3]; B.v4 = lv[ww][row64][st][4];
      B.i0 = li[ww][row64][st][0]; B.i1 = li[ww][row64][st][1]; B.i2 = li[ww][row64][st][2];
      B.i3 = li[ww][row64][st][3]; B.i4 = li[ww][row64][st][4];
      mergeL(A, B);
    }
    int grow = bty + row64;
    size_t pbase = ((size_t)tile * CNR + grow) * 20 + st * 5;
    pv[pbase + 0] = A.v0; pv[pbase + 1] = A.v1; pv[pbase + 2] = A.v2;
    pv[pbase + 3] = A.v3; pv[pbase + 4] = A.v4;
    pi[pbase + 0] = (unsigned short)A.i0; pi[pbase + 1] = (unsigned short)A.i1;
    pi[pbase + 2] = (unsigned short)A.i2; pi[pbase + 3] = (unsigned short)A.i3;
    pi[pbase + 4] = (unsigned short)A.i4;
    if (st == 0) {
      float m = lms[0][row64][0], s = lms[0][row64][1];
#pragma unroll
      for (int ww = 1; ww < 4; ++ww) {
        float m2 = lms[ww][row64][0], s2 = lms[ww][row64][1];
        float mn = fmaxf(m, m2);
        s = s * expf(m - mn) + s2 * expf(m2 - mn);
        m = mn;
      }
      pms[((size_t)tile * CNR + grow) * 2 + 0] = m;
      pms[((size_t)tile * CNR + grow) * 2 + 1] = s;
    }
  }
}

// ---------------- per-row reduce over 79 tiles: final top5 per st + lse --------------
// block = one row, 64 threads: st = t>>4, chunk c = t&15 (5 tiles each)
template <bool INIT>
__global__ __launch_bounds__(64) void reduce_k(
    const float* __restrict__ pv, const unsigned short* __restrict__ pi,
    const float* __restrict__ pms, const unsigned char* __restrict__ pmask,
    const int* __restrict__ lastp_in,
    float* __restrict__ fin_v, int* __restrict__ fin_i, float* __restrict__ lsebuf,
    float* __restrict__ lp0, int* __restrict__ preds0,
    int* __restrict__ lastp_out, int* __restrict__ rowmap) {
  int row = blockIdx.x;
  int t = threadIdx.x;
  int st = t >> 4, c = t & 15;
  L5 A;
  initL(A);
  float m = NEGINF, s = 0.f;
  for (int j = 0; j < 5; ++j) {
    int tl = c * 5 + j;
    if (tl >= NTILE) break;
    size_t base = ((size_t)tl * CNR + row) * 20 + st * 5;
    L5 B;
    B.v0 = pv[base + 0]; B.v1 = pv[base + 1]; B.v2 = pv[base + 2];
    B.v3 = pv[base + 3]; B.v4 = pv[base + 4];
    B.i0 = pi[base + 0]; B.i1 = pi[base + 1]; B.i2 = pi[base + 2];
    B.i3 = pi[base + 3]; B.i4 = pi[base + 4];
    mergeL(A, B);
    if (st == 0) {
      float mt = pms[((size_t)tl * CNR + row) * 2 + 0];
      float stv = pms[((size_t)tl * CNR + row) * 2 + 1];
      float mn = fmaxf(m, mt);
      s = s * expf(m - mn) + stv * expf(mt - mn);
      m = mn;
    }
  }
  __shared__ float shv[4][16][5];
  __shared__ int shi[4][16][5];
  __shared__ float shm[16], shs[16];
  __shared__ float shlse;
  shv[st][c][0] = A.v0; shv[st][c][1] = A.v1; shv[st][c][2] = A.v2;
  shv[st][c][3] = A.v3; shv[st][c][4] = A.v4;
  shi[st][c][0] = A.i0; shi[st][c][1] = A.i1; shi[st][c][2] = A.i2;
  shi[st][c][3] = A.i3; shi[st][c][4] = A.i4;
  if (st == 0) { shm[c] = m; shs[c] = s; }
  for (int off = 8; off >= 1; off >>= 1) {
    __syncthreads();
    if (c < off) {
      L5 B;
      B.v0 = shv[st][c + off][0]; B.v1 = shv[st][c + off][1]; B.v2 = shv[st][c + off][2];
      B.v3 = shv[st][c + off][3]; B.v4 = shv[st][c + off][4];
      B.i0 = shi[st][c + off][0]; B.i1 = shi[st][c + off][1]; B.i2 = shi[st][c + off][2];
      B.i3 = shi[st][c + off][3]; B.i4 = shi[st][c + off][4];
      mergeL(A, B);
      shv[st][c][0] = A.v0; shv[st][c][1] = A.v1; shv[st][c][2] = A.v2;
      shv[st][c][3] = A.v3; shv[st][c][4] = A.v4;
      shi[st][c][0] = A.i0; shi[st][c][1] = A.i1; shi[st][c][2] = A.i2;
      shi[st][c][3] = A.i3; shi[st][c][4] = A.i4;
      if (st == 0) {
        float m2 = shm[c + off], s2 = shs[c + off];
        float mn = fmaxf(m, m2);
        s = s * expf(m - mn) + s2 * expf(m2 - mn);
        m = mn;
        shm[c] = m; shs[c] = s;
      }
    }
  }
  __syncthreads();
  if (t == 0) shlse = shm[0] + logf(shs[0]);
  __syncthreads();
  float lse = shlse;
  if (c == 0) {
    if (INIT) {
      // row = b ; write LP0 (= raw - lse), preds0, lastp, rowmap
      float vv[5] = {A.v0, A.v1, A.v2, A.v3, A.v4};
      int ii[5] = {A.i0, A.i1, A.i2, A.i3, A.i4};
      int slot = row * CSB + st * 5;
#pragma unroll
      for (int k = 0; k < 5; ++k) {
        lp0[slot + k] = vv[k] - lse;
        preds0[slot + k] = ii[k];
        lastp_out[slot + k] = ii[k];
        rowmap[slot + k] = row;
      }
    } else {
      bool ended = (lastp_in[row] == 0);
      if (ended) {
        int b = row / CSB, ss = (row % CSB) / CBEAM;
        unsigned char mb = pmask[(size_t)(b * CS + ss) * CV];
        A.v0 = ((mb >> st) & 1) ? 0.0f : VNF; A.i0 = 0;
        A.v1 = VNF; A.i1 = 1; A.v2 = VNF; A.i2 = 2;
        A.v3 = VNF; A.i3 = 3; A.v4 = VNF; A.i4 = 4;
      }
      size_t fb = ((size_t)row * 4 + st) * 5;
      fin_v[fb + 0] = A.v0; fin_v[fb + 1] = A.v1; fin_v[fb + 2] = A.v2;
      fin_v[fb + 3] = A.v3; fin_v[fb + 4] = A.v4;
      fin_i[fb + 0] = A.i0; fin_i[fb + 1] = A.i1; fin_i[fb + 2] = A.i2;
      fin_i[fb + 3] = A.i3; fin_i[fb + 4] = A.i4;
      if (st == 0) lsebuf[row] = ended ? 0.f : lse;
    }
  }
}

// ---------------- beam selection: top-5 of 100 candidates per (b, st) ----------------
__global__ __launch_bounds__(128) void beam_sel_k(
    const float* __restrict__ fin_v, const int* __restrict__ fin_i,
    const float* __restrict__ lsebuf,
    const float* __restrict__ lp_old, float* __restrict__ lp_new,
    int* __restrict__ last_preds, int* __restrict__ rowmap,
    int* __restrict__ preds_t, int* __restrict__ bps_t) {
  int b = blockIdx.x / CS, st = blockIdx.x % CS;
  int tid = threadIdx.x;
  __shared__ float sv[128];
  __shared__ int si[128];
  float val = NEGINF;
  int idx = IMAX;
  if (tid < 100) {
    int r5 = tid / 5, k = tid % 5;
    int row = b * CSB + r5;
    val = fin_v[((size_t)row * 4 + st) * 5 + k] - lsebuf[row] + lp_old[row];
    idx = tid;
  }
  for (int r = 0; r < 5; ++r) {
    sv[tid] = val;
    si[tid] = idx;
    __syncthreads();
    for (int off = 64; off > 0; off >>= 1) {
      if (tid < off) {
        float w = sv[tid + off];
        int wi = si[tid + off];
        if (w > sv[tid] || (w == sv[tid] && wi < si[tid])) { sv[tid] = w; si[tid] = wi; }
      }
      __syncthreads();
    }
    float wval = sv[0];
    int widx = si[0];
    if (idx == widx) { val = NEGINF; idx = IMAX; }
    if (tid == r) {
      int r5 = widx / 5, k = widx % 5;
      int row = b * CSB + r5;
      int pred = fin_i[((size_t)row * 4 + st) * 5 + k];
      int bp = r5;  // ss*5+beam
      int slot = (b * CS + st) * CBEAM + r;
      lp_new[slot] = wval;
      preds_t[slot] = pred;
      bps_t[slot] = bp;
      last_preds[slot] = pred;
      rowmap[slot] = b * CSB + bp;
    }
    __syncthreads();
  }
}

// ---------------- backtrack + write outputs ----------------
__global__ void backtrack_k(const int* __restrict__ preds, const int* __restrict__ bps,
                            const float* __restrict__ lpfin, float* __restrict__ out) {
  int b = blockIdx.x, j = threadIdx.x;
  if (j >= CSB) return;
  int s = j / CBEAM, bm = j % CBEAM;
  int obase = ((b * CS + s) * CBEAM + bm) * CT;
  int tok = preds[(CT - 1) * CNR + b * CSB + j];
  out[obase + CT - 1] = (float)tok;
  int cur = bps[(CT - 2) * CNR + b * CSB + j];
  for (int t = CT - 2; t >= 1; --t) {
    tok = preds[t * CNR + b * CSB + cur];
    out[obase + t] = (float)tok;
    cur = bps[(t - 1) * CNR + b * CSB + cur];
  }
  tok = preds[0 * CNR + b * CSB + cur];
  out[obase + 0] = (float)tok;
  out[CB * CS * CBEAM * CT + b * CSB + j] = lpfin[b * CSB + j];
}

}  // namespace

extern "C" void kernel_launch(void* const* d_in, const int* in_sizes, int n_in,
                              void* d_out, int out_size, void* d_ws, size_t ws_size,
                              hipStream_t stream) {
  (void)in_sizes; (void)n_in; (void)out_size; (void)ws_size;
  const float* img = (const float*)d_in[0];
  const int* startp = (const int*)d_in[1];
  const void* straw = d_in[2];
  const float* emb = (const float*)d_in[3];
  const float* Wh = (const float*)d_in[4];
  const float* Wim = (const float*)d_in[5];
  const float* Wout = (const float*)d_in[6];
  float* out = (float*)d_out;

  char* ws = (char*)d_ws;
  size_t off = 0;
  auto take = [&](size_t bytes) -> char* {
    char* p = ws + off;
    off += (bytes + 255) & ~(size_t)255;
    return p;
  };
  unsigned char* pmask = (unsigned char*)take((size_t)CNP + 512);  // +pad for u32 overread
  int* modep = (int*)take(256);
  float* imgproj = (float*)take((size_t)CB * CH * 4);
  float* H0 = (float*)take((size_t)CNR * CH * 4);
  float* H1 = (float*)take((size_t)CNR * CH * 4);
  float* lsebuf = (float*)take((size_t)CNR * 4);
  float* LP0 = (float*)take((size_t)CNR * 4);
  float* LP1 = (float*)take((size_t)CNR * 4);
  int* lastp = (int*)take((size_t)CNR * 4);
  int* rowmap = (int*)take((size_t)CNR * 4);
  int* predsq = (int*)take((size_t)CT * CNR * 4);
  int* bpsq = (int*)take((size_t)(CT - 1) * CNR * 4);
  f16* BTh = (f16*)take((size_t)CVP * CH * 2);
  f16* BTl = (f16*)take((size_t)CVP * CH * 2);
  f16* Hh = (f16*)take((size_t)CNR * CH * 2);
  f16* Hl = (f16*)take((size_t)CNR * CH * 2);
  float* pv = (float*)take((size_t)NTILE * CNR * 20 * 4);
  unsigned short* pi = (unsigned short*)take((size_t)NTILE * CNR * 20 * 2);
  float* pms = (float*)take((size_t)NTILE * CNR * 2 * 4);
  float* finv = (float*)take((size_t)CNR * 4 * 5 * 4);
  int* fini = (int*)take((size_t)CNR * 4 * 5 * 4);

  detect_mode_k<<<1, 64, 0, stream>>>((const unsigned int*)straw, modep);
  convert_pack_k<<<1024, 256, 0, stream>>>(straw, pmask, modep);
  conv_wout_k<<<dim3(CVP / 64, CH / 64), 256, 0, stream>>>(Wout, BTh, BTl);
  img_proj_k<<<CB, 256, 0, stream>>>(img, Wim, imgproj);
  init_h_k<<<CB, 256, 0, stream>>>(emb, startp, imgproj, H0, Hh, Hl);

  fused_gemm_k<true><<<dim3(NTILE, 1), 256, 0, stream>>>(Hh, Hl, BTh, BTl, pmask, pv, pi, pms);
  reduce_k<true><<<CB, 64, 0, stream>>>(pv, pi, pms, pmask, nullptr, nullptr, nullptr,
                                        nullptr, LP0, predsq, lastp, rowmap);
  for (int t = 1; t < CT; ++t) {
    float* hprev = (t & 1) ? H0 : H1;
    float* hcur = (t & 1) ? H1 : H0;
    float* lpold = (t & 1) ? LP0 : LP1;
    float* lpnew = (t & 1) ? LP1 : LP0;
    gemm_k<32, 64, 32, 2, 4><<<dim3(8, 20), 256, 0, stream>>>(
        hprev, rowmap, Wh, hcur, CNR, CH, CH, lastp, emb, imgproj, Hh, Hl);
    fused_gemm_k<false><<<dim3(NTILE, 10), 256, 0, stream>>>(Hh, Hl, BTh, BTl, pmask, pv, pi, pms);
    reduce_k<false><<<CNR, 64, 0, stream>>>(pv, pi, pms, pmask, lastp, finv, fini, lsebuf,
                                            nullptr, nullptr, nullptr, nullptr);
    beam_sel_k<<<CB * CS, 128, 0, stream>>>(finv, fini, lsebuf, lpold, lpnew, lastp, rowmap,
                                            predsq + (size_t)t * CNR,
                                            bpsq + (size_t)(t - 1) * CNR);
  }
  backtrack_k<<<CB, 32, 0, stream>>>(predsq, bpsq, LP1, out);
}